// Round 3
// baseline (223.025 us; speedup 1.0000x reference)
//
#include <hip/hip_runtime.h>

typedef __attribute__((ext_vector_type(8))) __bf16 bfv8;
typedef __attribute__((ext_vector_type(4))) float f4v;
typedef __attribute__((ext_vector_type(4))) unsigned short us4v;
typedef __attribute__((ext_vector_type(8))) unsigned short us8v;

static __device__ __forceinline__ unsigned short f2bf(float f){
  union { float f; unsigned u; } v; v.f = f;
  unsigned r = v.u + 0x7fffu + ((v.u >> 16) & 1u);
  return (unsigned short)(r >> 16);
}

static __device__ __forceinline__ unsigned cvtpk(float a, float b){
  unsigned r;
  asm("v_cvt_pk_bf16_f32 %0, %1, %2" : "=v"(r) : "v"(a), "v"(b));
  return r;
}

static __device__ __forceinline__ f4v mfma16(bfv8 a, bfv8 b, f4v c){
  return __builtin_amdgcn_mfma_f32_16x16x32_bf16(a, b, c, 0, 0, 0);
}

// ---------------- K0: fp32 -> bf16 convert (weights) ----------------
__global__ __launch_bounds__(256) void k_cvt(const float* __restrict__ src,
                                             unsigned short* __restrict__ dst){
  int i = blockIdx.x * 256 + threadIdx.x;
  float4 v = ((const float4*)src)[i];
  us4v o; o[0]=f2bf(v.x); o[1]=f2bf(v.y); o[2]=f2bf(v.z); o[3]=f2bf(v.w);
  *(us4v*)(dst + (size_t)i*4) = o;
}

// ---------------- K1: GroupNorm partial stats ----------------
__global__ __launch_bounds__(256) void k_gnstat(const float* __restrict__ x,
                                                float2* __restrict__ part){
  int bg = blockIdx.x >> 4, ch = blockIdx.x & 15;
  const float4* base = (const float4*)(x + (size_t)bg*131072 + (size_t)ch*8192);
  float s=0.f, ss=0.f;
  #pragma unroll
  for (int it=0; it<8; ++it){
    float4 v = base[threadIdx.x + it*256];
    s  += v.x+v.y+v.z+v.w;
    ss += v.x*v.x+v.y*v.y+v.z*v.z+v.w*v.w;
  }
  #pragma unroll
  for (int off=1; off<64; off<<=1){ s += __shfl_xor(s,off); ss += __shfl_xor(ss,off); }
  __shared__ float red[8];
  int wid = threadIdx.x >> 6, l = threadIdx.x & 63;
  if (l==0){ red[wid]=s; red[wid+4]=ss; }
  __syncthreads();
  if (threadIdx.x==0)
    part[blockIdx.x] = make_float2(red[0]+red[1]+red[2]+red[3],
                                   red[4]+red[5]+red[6]+red[7]);
}

// ---------------- K2: GroupNorm finalize + transpose to hT[b][n][c] bf16 ----------------
__global__ __launch_bounds__(256) void k_gnnorm(const float* __restrict__ x,
                                                const float2* __restrict__ part,
                                                const float* __restrict__ gnw,
                                                const float* __restrict__ gnb,
                                                unsigned short* __restrict__ hT){
  int nt = blockIdx.x & 31, ct = (blockIdx.x>>5)&7, b = blockIdx.x>>8;
  __shared__ float2 sms;
  __shared__ unsigned short tile[64][68];
  int tid = threadIdx.x;
  if (tid == 0){
    int bg = b*8 + ct;
    float s=0.f, ss=0.f;
    for (int i=0;i<16;++i){ float2 p = part[bg*16+i]; s+=p.x; ss+=p.y; }
    float mean = s * (1.f/131072.f);
    float var  = ss * (1.f/131072.f) - mean*mean;
    sms = make_float2(mean, rsqrtf(var + 1e-5f));
  }
  __syncthreads();
  float mean = sms.x, rstd = sms.y;
  int c0 = ct*64, n0 = nt*64;
  #pragma unroll
  for (int pass=0; pass<4; ++pass){
    int i = (tid>>4) + pass*16;
    int fc = tid & 15;
    int c = c0 + i;
    float w  = gnw[c]*rstd;
    float bb = gnb[c] - mean*w;
    float4 v = *(const float4*)(x + ((size_t)(b*512+c))*2048 + n0 + fc*4);
    tile[i][fc*4+0] = f2bf(v.x*w+bb);
    tile[i][fc*4+1] = f2bf(v.y*w+bb);
    tile[i][fc*4+2] = f2bf(v.z*w+bb);
    tile[i][fc*4+3] = f2bf(v.w*w+bb);
  }
  __syncthreads();
  #pragma unroll
  for (int pass=0; pass<2; ++pass){
    int r  = (tid>>3) + pass*32;
    int c8 = tid & 7;
    us8v o;
    #pragma unroll
    for (int u=0;u<8;++u) o[u] = tile[c8*8+u][r];
    *(us8v*)(hT + ((size_t)(b*2048 + n0 + r))*512 + c0 + c8*8) = o;
  }
}

// ---------------- K3: qkv GEMM ----------------
__global__ __launch_bounds__(256) void k_qkv(const unsigned short* __restrict__ hT,
                                             const unsigned short* __restrict__ wb,
                                             const float* __restrict__ qb,
                                             unsigned short* __restrict__ Qh,
                                             unsigned short* __restrict__ Kh,
                                             unsigned short* __restrict__ Vt){
  int bid = blockIdx.x;
  int ot = bid % 12; int t2 = bid / 12; int nt = t2 & 31; int b = t2 >> 5;
  int tid = threadIdx.x, wid = tid>>6, l = tid&63, lr = l&15, lg = l>>4;
  int n0 = nt*64 + wid*16, o0 = ot*128;
  f4v acc[8];
  #pragma unroll
  for (int s=0;s<8;++s) acc[s] = (f4v){0.f,0.f,0.f,0.f};
  const unsigned short* arow = hT + ((size_t)(b*2048 + n0 + lr))*512 + lg*8;
  const unsigned short* brow = wb + (size_t)(o0 + lr)*512 + lg*8;
  for (int k=0;k<512;k+=32){
    bfv8 a = *(const bfv8*)(arow + k);
    #pragma unroll
    for (int s=0;s<8;++s){
      bfv8 bb = *(const bfv8*)(brow + s*8192 + k);
      acc[s] = mfma16(a, bb, acc[s]);
    }
  }
  #pragma unroll
  for (int s=0;s<8;++s){
    int o = o0 + s*16 + lr;
    float bias = qb[o];
    int seg = o >> 9, oo = o & 511, h = oo>>6, dd = oo&63;
    #pragma unroll
    for (int r=0;r<4;++r){
      int n = n0 + lg*4 + r;
      unsigned short val = f2bf(acc[s][r] + bias);
      if (seg==0)      Qh[(((size_t)(b*8+h))*2048+n)*64 + dd] = val;
      else if (seg==1) Kh[(((size_t)(b*8+h))*2048+n)*64 + dd] = val;
      else             Vt[(((size_t)(b*8+h))*64+dd)*2048 + n] = val;
    }
  }
}

// ---------------- K4: flash attention v3 ----------------
// 16 q-rows per block; 4 waves split KV 4-ways (512 each); static-max softmax so
// partials are additive; LDS combine. Grid 2048 = full occupancy.
__global__ __launch_bounds__(256) void k_attn(const unsigned short* __restrict__ Qh,
                                              const unsigned short* __restrict__ Kh,
                                              const unsigned short* __restrict__ Vt,
                                              const float* __restrict__ rel,
                                              unsigned short* __restrict__ AO){
  int did = blockIdx.x;
  int bh = (did & 7)*2 + ((did >> 10) & 1);   // XCD-chunked: 2 heads per XCD
  int qt = (did >> 3) & 127;                  // 128 q-tiles of 16 rows
  int tid = threadIdx.x, wid = tid>>6, l = tid&63, lr = l&15, lg = l>>4;
  __shared__ float slut[32];
  __shared__ __align__(16) char smem[17408];  // pbuf[4][2048B] unioned with sO[4][16][66]f32
  __shared__ float slsum[4][16];
  unsigned short* pbuf = (unsigned short*)smem;
  float (*sO)[16][66] = (float (*)[16][66])smem;
  if (tid < 32){
    int bkt = (tid>=1)+(tid>=4)+(tid>=9)+(tid>=16)+(tid>=25);
    slut[tid] = rel[bkt];
  }
  __syncthreads();
  int q0 = qt*16;
  int dq = q0 >> 8, hq = (q0 >> 4) & 15;      // wave-uniform (q0 is 16-aligned)
  int swsq[4];
  #pragma unroll
  for (int r=0;r<4;++r){ int sw = lr - (lg*4+r); swsq[r] = sw*sw; }
  const unsigned short* Qb = Qh + (size_t)bh*131072;
  const unsigned short* Kb = Kh + (size_t)bh*131072;
  const unsigned short* Vb = Vt + (size_t)bh*131072;
  bfv8 qf0 = *(const bfv8*)(Qb + (size_t)(q0+lr)*64 + lg*8);
  bfv8 qf1 = *(const bfv8*)(Qb + (size_t)(q0+lr)*64 + 32 + lg*8);
  f4v oacc[4];
  #pragma unroll
  for (int i2=0;i2<4;++i2) oacc[i2] = (f4v){0.f,0.f,0.f,0.f};
  float lsumL = 0.f;
  char* pw = (char*)(pbuf + wid*1024);
  int swz = (lr&7)<<4;
  for (int it=0; it<8; ++it){
    int itg = wid*8 + it;                     // global 64-KV tile index
    int jb = itg*64;
    f4v sacc[4];
    #pragma unroll
    for (int t=0;t<4;++t) sacc[t] = (f4v){0.f,0.f,0.f,0.f};
    #pragma unroll
    for (int t=0;t<4;++t){
      const unsigned short* kr = Kb + (size_t)(jb + t*16 + lr)*64 + lg*8;
      sacc[t] = mfma16(*(const bfv8*)kr, qf0, sacc[t]);        // S^T: A=K rows, B=Q rows
      sacc[t] = mfma16(*(const bfv8*)(kr+32), qf1, sacc[t]);
    }
    int sdh[4];
    {
      int dj = itg>>2; int sd = dq-dj; int sds = sd*sd;
      int hj0 = (itg&3)*4;
      #pragma unroll
      for (int t=0;t<4;++t){ int sh = hq - (hj0+t); sdh[t] = sds + sh*sh; }
    }
    float p[4][4];
    #pragma unroll
    for (int t=0;t<4;++t){
      #pragma unroll
      for (int r=0;r<4;++r){
        float bias = slut[(sdh[t]+swsq[r])>>4];
        float e = __expf(fmaf(sacc[t][r], 0.125f, bias));
        p[t][r] = e;
        lsumL += e;
      }
    }
    #pragma unroll
    for (int t=0;t<4;++t){
      uint2 w;
      w.x = cvtpk(p[t][0], p[t][1]);
      w.y = cvtpk(p[t][2], p[t][3]);
      *(uint2*)(pw + lr*128 + ((32*t + 8*lg) ^ swz)) = w;
    }
    #pragma unroll
    for (int kt=0;kt<2;++kt){
      bfv8 pf = *(const bfv8*)(pw + lr*128 + ((64*kt + 16*lg) ^ swz));
      #pragma unroll
      for (int d2=0;d2<4;++d2){
        bfv8 vf = *(const bfv8*)(Vb + (size_t)(d2*16+lr)*2048 + jb + kt*32 + lg*8);
        oacc[d2] = mfma16(pf, vf, oacc[d2]);
      }
    }
  }
  lsumL += __shfl_xor(lsumL, 16);
  lsumL += __shfl_xor(lsumL, 32);
  __syncthreads();                 // all waves done with pbuf; safe to reuse as sO
  #pragma unroll
  for (int r=0;r<4;++r){
    #pragma unroll
    for (int d2=0;d2<4;++d2)
      sO[wid][lg*4+r][d2*16+lr] = oacc[d2][r];
  }
  if (l < 16) slsum[wid][lr] = lsumL;
  __syncthreads();
  int b = bh>>3, h = bh&7;
  int col = tid & 63, r0 = tid >> 6;
  #pragma unroll
  for (int k=0;k<4;++k){
    int row = r0*4 + k;
    float os = sO[0][row][col] + sO[1][row][col] + sO[2][row][col] + sO[3][row][col];
    float ls = slsum[0][row] + slsum[1][row] + slsum[2][row] + slsum[3][row];
    AO[((size_t)(b*2048) + q0 + row)*512 + h*64 + col] = f2bf(os/ls);
  }
}

// ---------------- K5: proj GEMM + bias + residual ----------------
__global__ __launch_bounds__(256) void k_proj(const unsigned short* __restrict__ AO,
                                              const unsigned short* __restrict__ wb,
                                              const float* __restrict__ pb,
                                              const float* __restrict__ x,
                                              float* __restrict__ out){
  int nt = blockIdx.x & 31, ot = (blockIdx.x>>5)&7, b = blockIdx.x>>8;
  int tid = threadIdx.x, wid = tid>>6, l = tid&63, lr = l&15, lg = l>>4;
  int o0 = ot*64 + wid*16, n0 = nt*64;
  f4v acc[4];
  #pragma unroll
  for (int t=0;t<4;++t) acc[t] = (f4v){0.f,0.f,0.f,0.f};
  const unsigned short* arow = wb + (size_t)(o0+lr)*512 + lg*8;
  const unsigned short* brow = AO + ((size_t)(b*2048)+n0+lr)*512 + lg*8;
  for (int k=0;k<512;k+=32){
    bfv8 a = *(const bfv8*)(arow + k);
    #pragma unroll
    for (int t=0;t<4;++t){
      bfv8 bb = *(const bfv8*)(brow + t*8192 + k);
      acc[t] = mfma16(a, bb, acc[t]);
    }
  }
  #pragma unroll
  for (int r=0;r<4;++r){
    int o = o0 + lg*4 + r;
    float bias = pb[o];
    #pragma unroll
    for (int t=0;t<4;++t){
      int n = n0 + t*16 + lr;
      size_t idx = ((size_t)(b*512)+o)*2048 + n;
      out[idx] = acc[t][r] + bias + x[idx];
    }
  }
}

extern "C" void kernel_launch(void* const* d_in, const int* in_sizes, int n_in,
                              void* d_out, int out_size, void* d_ws, size_t ws_size,
                              hipStream_t stream){
  const float* x     = (const float*)d_in[0];
  const float* gnw   = (const float*)d_in[1];
  const float* gnb   = (const float*)d_in[2];
  const float* qkvw  = (const float*)d_in[3];
  const float* qkvb  = (const float*)d_in[4];
  const float* projw = (const float*)d_in[5];
  const float* projb = (const float*)d_in[6];
  const float* rel   = (const float*)d_in[7];
  float* out = (float*)d_out;
  char* ws = (char*)d_ws;
  float2* part           = (float2*)ws;                       // 2 KB
  unsigned short* qkvwb  = (unsigned short*)(ws + 4096);      // 1536x512 bf16
  unsigned short* projwb = (unsigned short*)(ws + 1576960);   // 512x512 bf16
  unsigned short* hT     = (unsigned short*)(ws + 2101248);   // [2][2048][512]
  unsigned short* Qh     = (unsigned short*)(ws + 6295552);   // [2][8][2048][64]
  unsigned short* Kh     = (unsigned short*)(ws + 10489856);  // [2][8][2048][64]
  unsigned short* Vt     = (unsigned short*)(ws + 14684160);  // [2][8][64][2048]
  unsigned short* AO     = (unsigned short*)(ws + 18878464);  // [2][2048][512]

  hipLaunchKernelGGL(k_cvt,    dim3(768),  dim3(256), 0, stream, qkvw, qkvwb);
  hipLaunchKernelGGL(k_cvt,    dim3(256),  dim3(256), 0, stream, projw, projwb);
  hipLaunchKernelGGL(k_gnstat, dim3(256),  dim3(256), 0, stream, x, part);
  hipLaunchKernelGGL(k_gnnorm, dim3(512),  dim3(256), 0, stream, x, part, gnw, gnb, hT);
  hipLaunchKernelGGL(k_qkv,    dim3(768),  dim3(256), 0, stream, hT, qkvwb, qkvb, Qh, Kh, Vt);
  hipLaunchKernelGGL(k_attn,   dim3(2048), dim3(256), 0, stream, Qh, Kh, Vt, rel, AO);
  hipLaunchKernelGGL(k_proj,   dim3(512),  dim3(256), 0, stream, AO, projwb, projb, x, out);
}

// Round 4
// 108.290 us; speedup vs baseline: 2.0595x; 2.0595x over previous
//
#include <hip/hip_runtime.h>

typedef __attribute__((ext_vector_type(8))) __bf16 bfv8;
typedef __attribute__((ext_vector_type(4))) float f4v;
typedef __attribute__((ext_vector_type(4))) unsigned short us4v;
typedef __attribute__((ext_vector_type(8))) unsigned short us8v;

static __device__ __forceinline__ unsigned short f2bf(float f){
  union { float f; unsigned u; } v; v.f = f;
  unsigned r = v.u + 0x7fffu + ((v.u >> 16) & 1u);
  return (unsigned short)(r >> 16);
}

static __device__ __forceinline__ unsigned cvtpk(float a, float b){
  unsigned r;
  asm("v_cvt_pk_bf16_f32 %0, %1, %2" : "=v"(r) : "v"(a), "v"(b));
  return r;
}

static __device__ __forceinline__ f4v mfma16(bfv8 a, bfv8 b, f4v c){
  return __builtin_amdgcn_mfma_f32_16x16x32_bf16(a, b, c, 0, 0, 0);
}

// Fragment layout for a [rows][512] bf16 matrix consumed as MFMA operand rows:
//   off = (row>>4)*8192 + (col>>5)*512 + ((col>>3)&3)*128 + (row&15)*8 + (col&7)
// so a wave's load for (rowtile, kc) is base + lane*8 shorts = contiguous 1KB.

// ---------------- K0: fp32 -> bf16 fragment-ordered convert (weights, C=512) ----------------
__global__ __launch_bounds__(256) void k_cvtfrag(const float* __restrict__ src,
                                                 unsigned short* __restrict__ dst){
  int i = blockIdx.x * 256 + threadIdx.x;
  int o = i >> 7, c4 = (i & 127) << 2;
  float4 v = *(const float4*)(src + (size_t)o*512 + c4);
  us4v w; w[0]=f2bf(v.x); w[1]=f2bf(v.y); w[2]=f2bf(v.z); w[3]=f2bf(v.w);
  size_t off = (size_t)(o>>4)*8192 + ((c4>>5)<<9) + (((c4>>3)&3)<<7) + ((o&15)<<3) + (c4&7);
  *(us4v*)(dst + off) = w;
}

// ---------------- K1: GroupNorm partial stats ----------------
__global__ __launch_bounds__(256) void k_gnstat(const float* __restrict__ x,
                                                float2* __restrict__ part){
  int bg = blockIdx.x >> 4, ch = blockIdx.x & 15;
  const float4* base = (const float4*)(x + (size_t)bg*131072 + (size_t)ch*8192);
  float s=0.f, ss=0.f;
  #pragma unroll
  for (int it=0; it<8; ++it){
    float4 v = base[threadIdx.x + it*256];
    s  += v.x+v.y+v.z+v.w;
    ss += v.x*v.x+v.y*v.y+v.z*v.z+v.w*v.w;
  }
  #pragma unroll
  for (int off=1; off<64; off<<=1){ s += __shfl_xor(s,off); ss += __shfl_xor(ss,off); }
  __shared__ float red[8];
  int wid = threadIdx.x >> 6, l = threadIdx.x & 63;
  if (l==0){ red[wid]=s; red[wid+4]=ss; }
  __syncthreads();
  if (threadIdx.x==0)
    part[blockIdx.x] = make_float2(red[0]+red[1]+red[2]+red[3],
                                   red[4]+red[5]+red[6]+red[7]);
}

// ---------------- K2: GroupNorm finalize + transpose -> AF fragment layout ----------------
__global__ __launch_bounds__(256) void k_gnnorm(const float* __restrict__ x,
                                                const float2* __restrict__ part,
                                                const float* __restrict__ gnw,
                                                const float* __restrict__ gnb,
                                                unsigned short* __restrict__ AF){
  int nt = blockIdx.x & 31, ct = (blockIdx.x>>5)&7, b = blockIdx.x>>8;
  __shared__ float2 sms;
  __shared__ unsigned short tile[64][68];
  int tid = threadIdx.x;
  if (tid == 0){
    int bg = b*8 + ct;
    float s=0.f, ss=0.f;
    for (int i=0;i<16;++i){ float2 p = part[bg*16+i]; s+=p.x; ss+=p.y; }
    float mean = s * (1.f/131072.f);
    float var  = ss * (1.f/131072.f) - mean*mean;
    sms = make_float2(mean, rsqrtf(var + 1e-5f));
  }
  __syncthreads();
  float mean = sms.x, rstd = sms.y;
  int c0 = ct*64, n0 = nt*64;
  #pragma unroll
  for (int pass=0; pass<4; ++pass){
    int i = (tid>>4) + pass*16;
    int fc = tid & 15;
    int c = c0 + i;
    float w  = gnw[c]*rstd;
    float bb = gnb[c] - mean*w;
    float4 v = *(const float4*)(x + ((size_t)(b*512+c))*2048 + n0 + fc*4);
    tile[i][fc*4+0] = f2bf(v.x*w+bb);
    tile[i][fc*4+1] = f2bf(v.y*w+bb);
    tile[i][fc*4+2] = f2bf(v.z*w+bb);
    tile[i][fc*4+3] = f2bf(v.w*w+bb);
  }
  __syncthreads();
  #pragma unroll
  for (int pass=0; pass<2; ++pass){
    int r  = (tid>>3) + pass*32;
    int c8 = tid & 7;
    us8v o;
    #pragma unroll
    for (int u=0;u<8;++u) o[u] = tile[c8*8+u][r];
    int n = n0 + r, c = c0 + c8*8;
    size_t off = (size_t)(b*128 + (n>>4))*8192 + ((c>>5)<<9) + (((c>>3)&3)<<7) + ((n&15)<<3);
    *(us8v*)(AF + off) = o;
  }
}

// ---------------- K3: qkv GEMM (fragment-ordered operands) ----------------
__global__ __launch_bounds__(256) void k_qkv(const unsigned short* __restrict__ AF,
                                             const unsigned short* __restrict__ WQF,
                                             const float* __restrict__ qb,
                                             unsigned short* __restrict__ Qh,
                                             unsigned short* __restrict__ KF,
                                             unsigned short* __restrict__ VF){
  int bid = blockIdx.x;
  int ot = bid % 12; int t2 = bid / 12; int nt = t2 & 31; int b = t2 >> 5;
  int tid = threadIdx.x, wid = tid>>6, l = tid&63, lr = l&15, lg = l>>4;
  int n0 = nt*64 + wid*16, o0 = ot*128;
  f4v acc[8];
  #pragma unroll
  for (int s=0;s<8;++s) acc[s] = (f4v){0.f,0.f,0.f,0.f};
  const unsigned short* arow = AF + (size_t)(b*128 + (n0>>4))*8192 + l*8;
  const unsigned short* brow = WQF + (size_t)(o0>>4)*8192 + l*8;
  #pragma unroll
  for (int kc=0;kc<16;++kc){
    bfv8 a = *(const bfv8*)(arow + kc*512);
    #pragma unroll
    for (int s=0;s<8;++s){
      bfv8 bb = *(const bfv8*)(brow + s*8192 + kc*512);
      acc[s] = mfma16(a, bb, acc[s]);
    }
  }
  #pragma unroll
  for (int s=0;s<8;++s){
    int o = o0 + s*16 + lr;
    float bias = qb[o];
    int seg = o >> 9, oo = o & 511, h = oo>>6, dd = oo&63;
    size_t hb = (size_t)(b*8+h)*131072;
    #pragma unroll
    for (int r=0;r<4;++r){
      int n = n0 + lg*4 + r;
      unsigned short val = f2bf(acc[s][r] + bias);
      if (seg==0)
        Qh[hb + (size_t)n*64 + dd] = val;
      else if (seg==1)
        KF[hb + (n>>4)*1024 + (dd>>5)*512 + ((dd>>3)&3)*128 + (n&15)*8 + (dd&7)] = val;
      else
        VF[hb + (n>>5)*2048 + (dd>>4)*512 + ((n>>3)&3)*128 + (dd&15)*8 + (n&7)] = val;
    }
  }
}

// ---------------- K4: flash attention v4 (fragment-direct loads) ----------------
// 16 q-rows/block, 4 waves split KV 4-ways, static-max softmax, additive partials.
__global__ __launch_bounds__(256) void k_attn(const unsigned short* __restrict__ Qh,
                                              const unsigned short* __restrict__ KF,
                                              const unsigned short* __restrict__ VF,
                                              const float* __restrict__ rel,
                                              unsigned short* __restrict__ AOF){
  int did = blockIdx.x;
  int bh = (did & 7)*2 + ((did >> 10) & 1);   // XCD-chunked: 2 heads per XCD
  int qt = (did >> 3) & 127;                  // 128 q-tiles of 16 rows
  int tid = threadIdx.x, wid = tid>>6, l = tid&63, lr = l&15, lg = l>>4;
  __shared__ float slut[32];
  __shared__ __align__(16) char smem[17408];  // pbuf[4][2048B] unioned with sO[4][16][66]f32
  __shared__ float slsum[4][16];
  unsigned short* pbuf = (unsigned short*)smem;
  float (*sO)[16][66] = (float (*)[16][66])smem;
  if (tid < 32){
    int bkt = (tid>=1)+(tid>=4)+(tid>=9)+(tid>=16)+(tid>=25);
    slut[tid] = rel[bkt];
  }
  __syncthreads();
  int q0 = qt*16;
  int dq = q0 >> 8, hq = (q0 >> 4) & 15;      // wave-uniform (q0 is 16-aligned)
  int swsq[4];
  #pragma unroll
  for (int r=0;r<4;++r){ int sw = lr - (lg*4+r); swsq[r] = sw*sw; }
  const unsigned short* Qb = Qh + (size_t)bh*131072;
  const unsigned short* Kb = KF + (size_t)bh*131072;
  const unsigned short* Vb = VF + (size_t)bh*131072;
  bfv8 qf0 = *(const bfv8*)(Qb + (size_t)(q0+lr)*64 + lg*8);
  bfv8 qf1 = *(const bfv8*)(Qb + (size_t)(q0+lr)*64 + 32 + lg*8);
  f4v oacc[4];
  #pragma unroll
  for (int i2=0;i2<4;++i2) oacc[i2] = (f4v){0.f,0.f,0.f,0.f};
  float lsumL = 0.f;
  char* pw = (char*)(pbuf + wid*1024);
  int swz = (lr&7)<<4;
  for (int it=0; it<8; ++it){
    int itg = wid*8 + it;                     // global 64-KV tile index
    f4v sacc[4];
    #pragma unroll
    for (int t=0;t<4;++t) sacc[t] = (f4v){0.f,0.f,0.f,0.f};
    #pragma unroll
    for (int t=0;t<4;++t){
      const unsigned short* kb = Kb + (size_t)(itg*4 + t)*1024 + l*8;
      sacc[t] = mfma16(*(const bfv8*)kb, qf0, sacc[t]);        // S^T: A=K rows, B=Q rows
      sacc[t] = mfma16(*(const bfv8*)(kb+512), qf1, sacc[t]);
    }
    int sdh[4];
    {
      int dj = itg>>2; int sd = dq-dj; int sds = sd*sd;
      int hj0 = (itg&3)*4;
      #pragma unroll
      for (int t=0;t<4;++t){ int sh = hq - (hj0+t); sdh[t] = sds + sh*sh; }
    }
    float p[4][4];
    #pragma unroll
    for (int t=0;t<4;++t){
      #pragma unroll
      for (int r=0;r<4;++r){
        float bias = slut[(sdh[t]+swsq[r])>>4];
        float e = __expf(fmaf(sacc[t][r], 0.125f, bias));
        p[t][r] = e;
        lsumL += e;
      }
    }
    #pragma unroll
    for (int t=0;t<4;++t){
      uint2 w;
      w.x = cvtpk(p[t][0], p[t][1]);
      w.y = cvtpk(p[t][2], p[t][3]);
      *(uint2*)(pw + lr*128 + ((32*t + 8*lg) ^ swz)) = w;
    }
    #pragma unroll
    for (int kt=0;kt<2;++kt){
      bfv8 pf = *(const bfv8*)(pw + lr*128 + ((64*kt + 16*lg) ^ swz));
      const unsigned short* vb = Vb + (size_t)(itg*2 + kt)*2048 + l*8;
      #pragma unroll
      for (int d2=0;d2<4;++d2)
        oacc[d2] = mfma16(pf, *(const bfv8*)(vb + d2*512), oacc[d2]);
    }
  }
  lsumL += __shfl_xor(lsumL, 16);
  lsumL += __shfl_xor(lsumL, 32);
  __syncthreads();                 // all waves done with pbuf; safe to reuse as sO
  #pragma unroll
  for (int r=0;r<4;++r){
    #pragma unroll
    for (int d2=0;d2<4;++d2)
      sO[wid][lg*4+r][d2*16+lr] = oacc[d2][r];
  }
  if (l < 16) slsum[wid][lr] = lsumL;
  __syncthreads();
  int b = bh>>3, h = bh&7;
  int col = tid & 63, r0 = tid >> 6;
  size_t obase = (size_t)(b*128 + qt)*8192 + (size_t)(h*2 + (col>>5))*512
               + ((col>>3)&3)*128 + (col&7);
  #pragma unroll
  for (int k=0;k<4;++k){
    int row = r0*4 + k;
    float os = sO[0][row][col] + sO[1][row][col] + sO[2][row][col] + sO[3][row][col];
    float ls = slsum[0][row] + slsum[1][row] + slsum[2][row] + slsum[3][row];
    AOF[obase + row*8] = f2bf(os/ls);
  }
}

// ---------------- K5: proj GEMM + bias + residual (fragment-ordered operands) ----------------
__global__ __launch_bounds__(256) void k_proj(const unsigned short* __restrict__ AOF,
                                              const unsigned short* __restrict__ WPF,
                                              const float* __restrict__ pb,
                                              const float* __restrict__ x,
                                              float* __restrict__ out){
  int nt = blockIdx.x & 31, ot = (blockIdx.x>>5)&7, b = blockIdx.x>>8;
  int tid = threadIdx.x, wid = tid>>6, l = tid&63, lr = l&15, lg = l>>4;
  int o0 = ot*64 + wid*16, n0 = nt*64;
  f4v acc[4];
  #pragma unroll
  for (int t=0;t<4;++t) acc[t] = (f4v){0.f,0.f,0.f,0.f};
  const unsigned short* arow = WPF + (size_t)(o0>>4)*8192 + l*8;
  const unsigned short* brow = AOF + (size_t)(b*128 + (n0>>4))*8192 + l*8;
  #pragma unroll
  for (int kc=0;kc<16;++kc){
    bfv8 a = *(const bfv8*)(arow + kc*512);
    #pragma unroll
    for (int t=0;t<4;++t){
      bfv8 bb = *(const bfv8*)(brow + t*8192 + kc*512);
      acc[t] = mfma16(a, bb, acc[t]);
    }
  }
  #pragma unroll
  for (int r=0;r<4;++r){
    int o = o0 + lg*4 + r;
    float bias = pb[o];
    #pragma unroll
    for (int t=0;t<4;++t){
      int n = n0 + t*16 + lr;
      size_t idx = ((size_t)(b*512)+o)*2048 + n;
      out[idx] = acc[t][r] + bias + x[idx];
    }
  }
}

extern "C" void kernel_launch(void* const* d_in, const int* in_sizes, int n_in,
                              void* d_out, int out_size, void* d_ws, size_t ws_size,
                              hipStream_t stream){
  const float* x     = (const float*)d_in[0];
  const float* gnw   = (const float*)d_in[1];
  const float* gnb   = (const float*)d_in[2];
  const float* qkvw  = (const float*)d_in[3];
  const float* qkvb  = (const float*)d_in[4];
  const float* projw = (const float*)d_in[5];
  const float* projb = (const float*)d_in[6];
  const float* rel   = (const float*)d_in[7];
  float* out = (float*)d_out;
  char* ws = (char*)d_ws;
  float2* part           = (float2*)ws;                       // 2 KB
  unsigned short* WQF    = (unsigned short*)(ws + 4096);      // 1536x512 bf16, frag order
  unsigned short* WPF    = (unsigned short*)(ws + 1576960);   // 512x512 bf16, frag order
  unsigned short* AF     = (unsigned short*)(ws + 2101248);   // [2][2048][512] frag order
  unsigned short* Qh     = (unsigned short*)(ws + 6295552);   // [2][8][2048][64] row-major
  unsigned short* KF     = (unsigned short*)(ws + 10489856);  // [2][8] K frag order
  unsigned short* VF     = (unsigned short*)(ws + 14684160);  // [2][8] V frag order
  unsigned short* AOF    = (unsigned short*)(ws + 18878464);  // [2][2048][512] frag order

  hipLaunchKernelGGL(k_cvtfrag, dim3(768),  dim3(256), 0, stream, qkvw, WQF);
  hipLaunchKernelGGL(k_cvtfrag, dim3(256),  dim3(256), 0, stream, projw, WPF);
  hipLaunchKernelGGL(k_gnstat,  dim3(256),  dim3(256), 0, stream, x, part);
  hipLaunchKernelGGL(k_gnnorm,  dim3(512),  dim3(256), 0, stream, x, part, gnw, gnb, AF);
  hipLaunchKernelGGL(k_qkv,     dim3(768),  dim3(256), 0, stream, AF, WQF, qkvb, Qh, KF, VF);
  hipLaunchKernelGGL(k_attn,    dim3(2048), dim3(256), 0, stream, Qh, KF, VF, rel, AOF);
  hipLaunchKernelGGL(k_proj,    dim3(512),  dim3(256), 0, stream, AOF, WPF, projb, x, out);
}

// Round 5
// 86.190 us; speedup vs baseline: 2.5876x; 1.2564x over previous
//
#include <hip/hip_runtime.h>

typedef __attribute__((ext_vector_type(8))) __bf16 bfv8;
typedef __attribute__((ext_vector_type(4))) float f4v;
typedef __attribute__((ext_vector_type(4))) unsigned short us4v;
typedef __attribute__((ext_vector_type(8))) unsigned short us8v;

static __device__ __forceinline__ unsigned short f2bf(float f){
  union { float f; unsigned u; } v; v.f = f;
  unsigned r = v.u + 0x7fffu + ((v.u >> 16) & 1u);
  return (unsigned short)(r >> 16);
}

static __device__ __forceinline__ unsigned cvtpk(float a, float b){
  unsigned r;
  asm("v_cvt_pk_bf16_f32 %0, %1, %2" : "=v"(r) : "v"(a), "v"(b));
  return r;
}

static __device__ __forceinline__ f4v mfma16(bfv8 a, bfv8 b, f4v c){
  return __builtin_amdgcn_mfma_f32_16x16x32_bf16(a, b, c, 0, 0, 0);
}

// Fragment layout for a [rows][512] bf16 matrix consumed as MFMA operand rows:
//   off = (row>>4)*8192 + (col>>5)*512 + ((col>>3)&3)*128 + (row&15)*8 + (col&7)
// so a wave's load for (rowtile, kc) is base + lane*8 shorts = contiguous 1KB.

// ---------------- K0: fp32 -> bf16 fragment-ordered convert (both weights) ----------------
__global__ __launch_bounds__(256) void k_cvtfrag2(const float* __restrict__ qkvw,
                                                  const float* __restrict__ projw,
                                                  unsigned short* __restrict__ WQF,
                                                  unsigned short* __restrict__ WPF){
  int bid = blockIdx.x;
  const float* src; unsigned short* dst; int i;
  if (bid < 768){ src = qkvw; dst = WQF; i = bid*256 + threadIdx.x; }
  else          { src = projw; dst = WPF; i = (bid-768)*256 + threadIdx.x; }
  int o = i >> 7, c4 = (i & 127) << 2;
  float4 v = *(const float4*)(src + (size_t)o*512 + c4);
  us4v w; w[0]=f2bf(v.x); w[1]=f2bf(v.y); w[2]=f2bf(v.z); w[3]=f2bf(v.w);
  size_t off = (size_t)(o>>4)*8192 + ((c4>>5)<<9) + (((c4>>3)&3)<<7) + ((o&15)<<3) + (c4&7);
  *(us4v*)(dst + off) = w;
}

// ---------------- K1: GroupNorm partial stats ----------------
__global__ __launch_bounds__(256) void k_gnstat(const float* __restrict__ x,
                                                float2* __restrict__ part){
  int bg = blockIdx.x >> 4, ch = blockIdx.x & 15;
  const float4* base = (const float4*)(x + (size_t)bg*131072 + (size_t)ch*8192);
  float s=0.f, ss=0.f;
  #pragma unroll
  for (int it=0; it<8; ++it){
    float4 v = base[threadIdx.x + it*256];
    s  += v.x+v.y+v.z+v.w;
    ss += v.x*v.x+v.y*v.y+v.z*v.z+v.w*v.w;
  }
  #pragma unroll
  for (int off=1; off<64; off<<=1){ s += __shfl_xor(s,off); ss += __shfl_xor(ss,off); }
  __shared__ float red[8];
  int wid = threadIdx.x >> 6, l = threadIdx.x & 63;
  if (l==0){ red[wid]=s; red[wid+4]=ss; }
  __syncthreads();
  if (threadIdx.x==0)
    part[blockIdx.x] = make_float2(red[0]+red[1]+red[2]+red[3],
                                   red[4]+red[5]+red[6]+red[7]);
}

// ---------------- K2: GroupNorm finalize + transpose -> AF fragment layout ----------------
__global__ __launch_bounds__(256) void k_gnnorm(const float* __restrict__ x,
                                                const float2* __restrict__ part,
                                                const float* __restrict__ gnw,
                                                const float* __restrict__ gnb,
                                                unsigned short* __restrict__ AF){
  int nt = blockIdx.x & 31, ct = (blockIdx.x>>5)&7, b = blockIdx.x>>8;
  __shared__ float2 sms;
  __shared__ unsigned short tile[64][68];
  int tid = threadIdx.x;
  if (tid == 0){
    int bg = b*8 + ct;
    float s=0.f, ss=0.f;
    for (int i=0;i<16;++i){ float2 p = part[bg*16+i]; s+=p.x; ss+=p.y; }
    float mean = s * (1.f/131072.f);
    float var  = ss * (1.f/131072.f) - mean*mean;
    sms = make_float2(mean, rsqrtf(var + 1e-5f));
  }
  __syncthreads();
  float mean = sms.x, rstd = sms.y;
  int c0 = ct*64, n0 = nt*64;
  #pragma unroll
  for (int pass=0; pass<4; ++pass){
    int i = (tid>>4) + pass*16;
    int fc = tid & 15;
    int c = c0 + i;
    float w  = gnw[c]*rstd;
    float bb = gnb[c] - mean*w;
    float4 v = *(const float4*)(x + ((size_t)(b*512+c))*2048 + n0 + fc*4);
    tile[i][fc*4+0] = f2bf(v.x*w+bb);
    tile[i][fc*4+1] = f2bf(v.y*w+bb);
    tile[i][fc*4+2] = f2bf(v.z*w+bb);
    tile[i][fc*4+3] = f2bf(v.w*w+bb);
  }
  __syncthreads();
  #pragma unroll
  for (int pass=0; pass<2; ++pass){
    int r  = (tid>>3) + pass*32;
    int c8 = tid & 7;
    us8v o;
    #pragma unroll
    for (int u=0;u<8;++u) o[u] = tile[c8*8+u][r];
    int n = n0 + r, c = c0 + c8*8;
    size_t off = (size_t)(b*128 + (n>>4))*8192 + ((c>>5)<<9) + (((c>>3)&3)<<7) + ((n&15)<<3);
    *(us8v*)(AF + off) = o;
  }
}

// ---------------- K3: qkv GEMM (fragment-ordered operands) ----------------
__global__ __launch_bounds__(256) void k_qkv(const unsigned short* __restrict__ AF,
                                             const unsigned short* __restrict__ WQF,
                                             const float* __restrict__ qb,
                                             unsigned short* __restrict__ Qh,
                                             unsigned short* __restrict__ KF,
                                             unsigned short* __restrict__ VF){
  int bid = blockIdx.x;
  int ot = bid % 12; int t2 = bid / 12; int nt = t2 & 31; int b = t2 >> 5;
  int tid = threadIdx.x, wid = tid>>6, l = tid&63, lr = l&15, lg = l>>4;
  int n0 = nt*64 + wid*16, o0 = ot*128;
  f4v acc[8];
  #pragma unroll
  for (int s=0;s<8;++s) acc[s] = (f4v){0.f,0.f,0.f,0.f};
  const unsigned short* arow = AF + (size_t)(b*128 + (n0>>4))*8192 + l*8;
  const unsigned short* brow = WQF + (size_t)(o0>>4)*8192 + l*8;
  #pragma unroll
  for (int kc=0;kc<16;++kc){
    bfv8 a = *(const bfv8*)(arow + kc*512);
    #pragma unroll
    for (int s=0;s<8;++s){
      bfv8 bb = *(const bfv8*)(brow + s*8192 + kc*512);
      acc[s] = mfma16(a, bb, acc[s]);
    }
  }
  #pragma unroll
  for (int s=0;s<8;++s){
    int o = o0 + s*16 + lr;
    float bias = qb[o];
    int seg = o >> 9, oo = o & 511, h = oo>>6, dd = oo&63;
    size_t hb = (size_t)(b*8+h)*131072;
    #pragma unroll
    for (int r=0;r<4;++r){
      int n = n0 + lg*4 + r;
      unsigned short val = f2bf(acc[s][r] + bias);
      if (seg==0)
        Qh[hb + (size_t)n*64 + dd] = val;
      else if (seg==1)
        KF[hb + (n>>4)*1024 + (dd>>5)*512 + ((dd>>3)&3)*128 + (n&15)*8 + (dd&7)] = val;
      else
        VF[hb + (n>>5)*2048 + (dd>>4)*512 + ((n>>3)&3)*128 + (dd&15)*8 + (n&7)] = val;
    }
  }
}

// ---------------- K4: flash attention v5 ----------------
// 32 q-rows per WAVE (two Q fragments sharing every K/V load), 4 waves split KV
// 4-ways, static-max softmax, additive partials, LDS combine. Grid 1024.
__global__ __launch_bounds__(256,4) void k_attn(const unsigned short* __restrict__ Qh,
                                                const unsigned short* __restrict__ KF,
                                                const unsigned short* __restrict__ VF,
                                                const float* __restrict__ rel,
                                                unsigned short* __restrict__ AOF){
  int did = blockIdx.x;
  int bh = (did & 7)*2 + ((did >> 9) & 1);    // XCD-chunked: 2 heads per XCD
  int qt = (did >> 3) & 63;                   // 64 q-tiles of 32 rows
  int tid = threadIdx.x, wid = tid>>6, l = tid&63, lr = l&15, lg = l>>4;
  __shared__ float slut[32];
  __shared__ __align__(16) char smem[33792];  // pbuf[4][4096B] unioned with sO[4][32][66]f32
  __shared__ float slsum[4][32];
  float (*sO)[32][66] = (float (*)[32][66])smem;
  if (tid < 32){
    int bkt = (tid>=1)+(tid>=4)+(tid>=9)+(tid>=16)+(tid>=25);
    slut[tid] = rel[bkt];
  }
  __syncthreads();
  int q0 = qt*32;
  int dq = q0 >> 8, hqA = (q0 >> 4) & 15, hqB = hqA + 1;  // wave-uniform
  int swsq[4];
  #pragma unroll
  for (int r=0;r<4;++r){ int sw = lr - (lg*4+r); swsq[r] = sw*sw; }
  const unsigned short* Qb = Qh + (size_t)bh*131072;
  const unsigned short* Kb = KF + (size_t)bh*131072;
  const unsigned short* Vb = VF + (size_t)bh*131072;
  bfv8 qf0A = *(const bfv8*)(Qb + (size_t)(q0+lr)*64 + lg*8);
  bfv8 qf1A = *(const bfv8*)(Qb + (size_t)(q0+lr)*64 + 32 + lg*8);
  bfv8 qf0B = *(const bfv8*)(Qb + (size_t)(q0+16+lr)*64 + lg*8);
  bfv8 qf1B = *(const bfv8*)(Qb + (size_t)(q0+16+lr)*64 + 32 + lg*8);
  f4v oA[4], oB[4];
  #pragma unroll
  for (int i2=0;i2<4;++i2){ oA[i2] = (f4v){0.f,0.f,0.f,0.f}; oB[i2] = (f4v){0.f,0.f,0.f,0.f}; }
  float lsA = 0.f, lsB = 0.f;
  char* pwA = smem + wid*4096;
  char* pwB = pwA + 2048;
  int swz = (lr&7)<<4;
  for (int it=0; it<8; ++it){
    int itg = wid*8 + it;                     // global 64-KV tile index
    f4v sa[4], sb[4];
    #pragma unroll
    for (int t=0;t<4;++t){ sa[t] = (f4v){0.f,0.f,0.f,0.f}; sb[t] = (f4v){0.f,0.f,0.f,0.f}; }
    #pragma unroll
    for (int t=0;t<4;++t){
      const unsigned short* kb = Kb + (size_t)(itg*4 + t)*1024 + l*8;
      bfv8 k0 = *(const bfv8*)kb;
      bfv8 k1 = *(const bfv8*)(kb + 512);
      sa[t] = mfma16(k0, qf0A, sa[t]);
      sa[t] = mfma16(k1, qf1A, sa[t]);
      sb[t] = mfma16(k0, qf0B, sb[t]);
      sb[t] = mfma16(k1, qf1B, sb[t]);
    }
    int dj = itg>>2; int sd = dq-dj; int sds = sd*sd;
    int hj0 = (itg&3)*4;
    // ---- half A softmax ----
    #pragma unroll
    for (int t=0;t<4;++t){
      int sh = hqA - (hj0+t); int sdh = sds + sh*sh;
      float p0 = __expf(fmaf(sa[t][0], 0.125f, slut[(sdh+swsq[0])>>4]));
      float p1 = __expf(fmaf(sa[t][1], 0.125f, slut[(sdh+swsq[1])>>4]));
      float p2 = __expf(fmaf(sa[t][2], 0.125f, slut[(sdh+swsq[2])>>4]));
      float p3 = __expf(fmaf(sa[t][3], 0.125f, slut[(sdh+swsq[3])>>4]));
      lsA += (p0+p1)+(p2+p3);
      uint2 w; w.x = cvtpk(p0,p1); w.y = cvtpk(p2,p3);
      *(uint2*)(pwA + lr*128 + ((32*t + 8*lg) ^ swz)) = w;
    }
    // ---- half B softmax ----
    #pragma unroll
    for (int t=0;t<4;++t){
      int sh = hqB - (hj0+t); int sdh = sds + sh*sh;
      float p0 = __expf(fmaf(sb[t][0], 0.125f, slut[(sdh+swsq[0])>>4]));
      float p1 = __expf(fmaf(sb[t][1], 0.125f, slut[(sdh+swsq[1])>>4]));
      float p2 = __expf(fmaf(sb[t][2], 0.125f, slut[(sdh+swsq[2])>>4]));
      float p3 = __expf(fmaf(sb[t][3], 0.125f, slut[(sdh+swsq[3])>>4]));
      lsB += (p0+p1)+(p2+p3);
      uint2 w; w.x = cvtpk(p0,p1); w.y = cvtpk(p2,p3);
      *(uint2*)(pwB + lr*128 + ((32*t + 8*lg) ^ swz)) = w;
    }
    // ---- PV: V loads shared by both halves ----
    #pragma unroll
    for (int kt=0;kt<2;++kt){
      bfv8 pfA = *(const bfv8*)(pwA + lr*128 + ((64*kt + 16*lg) ^ swz));
      bfv8 pfB = *(const bfv8*)(pwB + lr*128 + ((64*kt + 16*lg) ^ swz));
      const unsigned short* vb = Vb + (size_t)(itg*2 + kt)*2048 + l*8;
      #pragma unroll
      for (int d2=0;d2<4;++d2){
        bfv8 vf = *(const bfv8*)(vb + d2*512);
        oA[d2] = mfma16(pfA, vf, oA[d2]);
        oB[d2] = mfma16(pfB, vf, oB[d2]);
      }
    }
  }
  lsA += __shfl_xor(lsA, 16); lsA += __shfl_xor(lsA, 32);
  lsB += __shfl_xor(lsB, 16); lsB += __shfl_xor(lsB, 32);
  __syncthreads();                 // all waves done with pbuf; reuse as sO
  #pragma unroll
  for (int r=0;r<4;++r){
    #pragma unroll
    for (int d2=0;d2<4;++d2){
      sO[wid][lg*4+r][d2*16+lr] = oA[d2][r];
      sO[wid][16+lg*4+r][d2*16+lr] = oB[d2][r];
    }
  }
  if (l < 16){ slsum[wid][lr] = lsA; slsum[wid][16+lr] = lsB; }
  __syncthreads();
  int b = bh>>3, h = bh&7;
  int col = tid & 63, r0 = tid >> 6;
  #pragma unroll
  for (int k=0;k<8;++k){
    int row = r0*8 + k;
    float os = sO[0][row][col] + sO[1][row][col] + sO[2][row][col] + sO[3][row][col];
    float ls = slsum[0][row] + slsum[1][row] + slsum[2][row] + slsum[3][row];
    int n = q0 + row;
    size_t off = (size_t)(b*128 + (n>>4))*8192 + (size_t)(h*2 + (col>>5))*512
               + ((col>>3)&3)*128 + ((n&15))*8 + (col&7);
    AOF[off] = f2bf(os/ls);
  }
}

// ---------------- K5: proj GEMM + bias + residual (fragment-ordered operands) ----------------
__global__ __launch_bounds__(256) void k_proj(const unsigned short* __restrict__ AOF,
                                              const unsigned short* __restrict__ WPF,
                                              const float* __restrict__ pb,
                                              const float* __restrict__ x,
                                              float* __restrict__ out){
  int nt = blockIdx.x & 31, ot = (blockIdx.x>>5)&7, b = blockIdx.x>>8;
  int tid = threadIdx.x, wid = tid>>6, l = tid&63, lr = l&15, lg = l>>4;
  int o0 = ot*64 + wid*16, n0 = nt*64;
  f4v acc[4];
  #pragma unroll
  for (int t=0;t<4;++t) acc[t] = (f4v){0.f,0.f,0.f,0.f};
  const unsigned short* arow = WPF + (size_t)(o0>>4)*8192 + l*8;
  const unsigned short* brow = AOF + (size_t)(b*128 + (n0>>4))*8192 + l*8;
  #pragma unroll
  for (int kc=0;kc<16;++kc){
    bfv8 a = *(const bfv8*)(arow + kc*512);
    #pragma unroll
    for (int t=0;t<4;++t){
      bfv8 bb = *(const bfv8*)(brow + t*8192 + kc*512);
      acc[t] = mfma16(a, bb, acc[t]);
    }
  }
  #pragma unroll
  for (int r=0;r<4;++r){
    int o = o0 + lg*4 + r;
    float bias = pb[o];
    #pragma unroll
    for (int t=0;t<4;++t){
      int n = n0 + t*16 + lr;
      size_t idx = ((size_t)(b*512)+o)*2048 + n;
      out[idx] = acc[t][r] + bias + x[idx];
    }
  }
}

extern "C" void kernel_launch(void* const* d_in, const int* in_sizes, int n_in,
                              void* d_out, int out_size, void* d_ws, size_t ws_size,
                              hipStream_t stream){
  const float* x     = (const float*)d_in[0];
  const float* gnw   = (const float*)d_in[1];
  const float* gnb   = (const float*)d_in[2];
  const float* qkvw  = (const float*)d_in[3];
  const float* qkvb  = (const float*)d_in[4];
  const float* projw = (const float*)d_in[5];
  const float* projb = (const float*)d_in[6];
  const float* rel   = (const float*)d_in[7];
  float* out = (float*)d_out;
  char* ws = (char*)d_ws;
  float2* part           = (float2*)ws;                       // 2 KB
  unsigned short* WQF    = (unsigned short*)(ws + 4096);      // 1536x512 bf16, frag order
  unsigned short* WPF    = (unsigned short*)(ws + 1576960);   // 512x512 bf16, frag order
  unsigned short* AF     = (unsigned short*)(ws + 2101248);   // [2][2048][512] frag order
  unsigned short* Qh     = (unsigned short*)(ws + 6295552);   // [2][8][2048][64] row-major
  unsigned short* KF     = (unsigned short*)(ws + 10489856);  // [2][8] K frag order
  unsigned short* VF     = (unsigned short*)(ws + 14684160);  // [2][8] V frag order
  unsigned short* AOF    = (unsigned short*)(ws + 18878464);  // [2][2048][512] frag order

  hipLaunchKernelGGL(k_cvtfrag2, dim3(1024), dim3(256), 0, stream, qkvw, projw, WQF, WPF);
  hipLaunchKernelGGL(k_gnstat,   dim3(256),  dim3(256), 0, stream, x, part);
  hipLaunchKernelGGL(k_gnnorm,   dim3(512),  dim3(256), 0, stream, x, part, gnw, gnb, AF);
  hipLaunchKernelGGL(k_qkv,      dim3(768),  dim3(256), 0, stream, AF, WQF, qkvb, Qh, KF, VF);
  hipLaunchKernelGGL(k_attn,     dim3(1024), dim3(256), 0, stream, Qh, KF, VF, rel, AOF);
  hipLaunchKernelGGL(k_proj,     dim3(512),  dim3(256), 0, stream, AOF, WPF, projb, x, out);
}